// Round 18
// baseline (258.124 us; speedup 1.0000x reference)
//
#include <hip/hip_runtime.h>
#include <hip/hip_bf16.h>

#define NNODES 12288
#define NEDGES (NNODES * 32)
#define ELLCAP 128  // max degree ~60 (Poisson(32) tail over 12288 rows); 128 unreachable

typedef __attribute__((ext_vector_type(4))) float f32x4;
typedef __attribute__((ext_vector_type(8))) __bf16 bf16x8;

// ---------------- fused prep: zero deg + 3 weight transpose-casts ----------------
__global__ __launch_bounds__(256) void prep_kernel(const float* __restrict__ W1,
                                                   const float* __restrict__ W2,
                                                   const float* __restrict__ W3,
                                                   __bf16* __restrict__ W1t,
                                                   __bf16* __restrict__ W2t,
                                                   __bf16* __restrict__ W3t,
                                                   int* __restrict__ deg) {
    int i = blockIdx.x * 256 + threadIdx.x;
    if (i < NNODES) { deg[i] = 0; return; }
    int j = i - NNODES;
    if (j < 512 * 256) { W1t[(size_t)(j % 256) * 512 + j / 256] = (__bf16)W1[j]; return; }
    j -= 512 * 256;
    if (j < 256 * 128) { W2t[(size_t)(j % 128) * 256 + j / 128] = (__bf16)W2[j]; return; }
    j -= 256 * 128;
    if (j < 128 * 64) { W3t[(size_t)(j % 64) * 128 + j / 64] = (__bf16)W3[j]; return; }
}

// ---------------- merged: gemm1 (blocks 0..383) + ELL scatter (blocks 384..1919) ----
__global__ __launch_bounds__(256) void gemm1_scatter(const float* __restrict__ x,
                                                     const __bf16* __restrict__ W1t,
                                                     __bf16* __restrict__ h1,
                                                     const int* __restrict__ erow,
                                                     const int* __restrict__ ecol,
                                                     const float* __restrict__ ew,
                                                     int* __restrict__ deg,
                                                     int2* __restrict__ ell) {
    if (blockIdx.x >= 384) {
        int e = (blockIdx.x - 384) * 256 + threadIdx.x;
        int r = erow[e];
        int p = atomicAdd(&deg[r], 1);
        int2 cw; cw.x = ecol[e]; cw.y = __float_as_int(ew[e]);
        ell[(size_t)r * ELLCAP + p] = cw;
        return;
    }
    // gemm1: h1 = tanh(x @ W1), K=512, Nc=256, f32 A cast in-register.
    constexpr int K = 512, Nc = 256;
    int wave = threadIdx.x >> 6, lane = threadIdx.x & 63;
    int lr = lane & 15, kg = lane >> 4;
    int m0 = (blockIdx.x % 96) * 128 + wave * 32;
    int n0 = (blockIdx.x / 96) * 64;
    f32x4 acc[2][4];
#pragma unroll
    for (int mi = 0; mi < 2; mi++)
#pragma unroll
        for (int ni = 0; ni < 4; ni++) acc[mi][ni] = (f32x4){0.f, 0.f, 0.f, 0.f};
#pragma unroll
    for (int k0 = 0; k0 < K; k0 += 32) {
        bf16x8 af[2], bf[4];
#pragma unroll
        for (int mi = 0; mi < 2; mi++) {
            const float* ap = x + (size_t)(m0 + mi * 16 + lr) * K + k0 + kg * 8;
            f32x4 a0 = *(const f32x4*)ap;
            f32x4 a1 = *(const f32x4*)(ap + 4);
#pragma unroll
            for (int j = 0; j < 4; j++) { af[mi][j] = (__bf16)a0[j]; af[mi][4 + j] = (__bf16)a1[j]; }
        }
#pragma unroll
        for (int ni = 0; ni < 4; ni++)
            bf[ni] = *(const bf16x8*)(W1t + (size_t)(n0 + ni * 16 + lr) * K + k0 + kg * 8);
#pragma unroll
        for (int mi = 0; mi < 2; mi++)
#pragma unroll
            for (int ni = 0; ni < 4; ni++)
                acc[mi][ni] = __builtin_amdgcn_mfma_f32_16x16x32_bf16(af[mi], bf[ni], acc[mi][ni], 0, 0, 0);
    }
    // C/D layout (m89-verified): col = lane&15, row = (lane>>4)*4 + reg
#pragma unroll
    for (int mi = 0; mi < 2; mi++)
#pragma unroll
        for (int ni = 0; ni < 4; ni++) {
            int col = n0 + ni * 16 + lr;
            int rowb = m0 + mi * 16 + kg * 4;
#pragma unroll
            for (int r = 0; r < 4; r++)
                h1[(size_t)(rowb + r) * Nc + col] = (__bf16)tanhf(acc[mi][ni][r]);
        }
}

// ---------------- generic dense GEMM (for g1 = h1 @ W2): bf16 MFMA ----------------
template <bool TANH, int K>
__global__ __launch_bounds__(256) void gemm_mfma(const __bf16* __restrict__ A,
                                                 const __bf16* __restrict__ Wt,
                                                 __bf16* __restrict__ C, int Nc) {
    int wave = threadIdx.x >> 6, lane = threadIdx.x & 63;
    int lr = lane & 15, kg = lane >> 4;
    int m0 = blockIdx.x * 128 + wave * 32;
    int n0 = blockIdx.y * 64;
    f32x4 acc[2][4];
#pragma unroll
    for (int mi = 0; mi < 2; mi++)
#pragma unroll
        for (int ni = 0; ni < 4; ni++) acc[mi][ni] = (f32x4){0.f, 0.f, 0.f, 0.f};
#pragma unroll
    for (int k0 = 0; k0 < K; k0 += 32) {
        bf16x8 af[2], bf[4];
#pragma unroll
        for (int mi = 0; mi < 2; mi++)
            af[mi] = *(const bf16x8*)(A + (size_t)(m0 + mi * 16 + lr) * K + k0 + kg * 8);
#pragma unroll
        for (int ni = 0; ni < 4; ni++)
            bf[ni] = *(const bf16x8*)(Wt + (size_t)(n0 + ni * 16 + lr) * K + k0 + kg * 8);
#pragma unroll
        for (int mi = 0; mi < 2; mi++)
#pragma unroll
            for (int ni = 0; ni < 4; ni++)
                acc[mi][ni] = __builtin_amdgcn_mfma_f32_16x16x32_bf16(af[mi], bf[ni], acc[mi][ni], 0, 0, 0);
    }
#pragma unroll
    for (int mi = 0; mi < 2; mi++)
#pragma unroll
        for (int ni = 0; ni < 4; ni++) {
            int col = n0 + ni * 16 + lr;
            int rowb = m0 + mi * 16 + kg * 4;
#pragma unroll
            for (int r = 0; r < 4; r++) {
                float v = acc[mi][ni][r];
                if (TANH) v = tanhf(v);
                C[(size_t)(rowb + r) * Nc + col] = (__bf16)v;
            }
        }
}

// ---------------- fusedB: h2 = tanh(spmm_F128(g1)); g2 = h2 @ W3 ----------------
__global__ __launch_bounds__(256) void fused_spmm_tanh_gemm(const int* __restrict__ deg,
                                                            const int2* __restrict__ ell,
                                                            const __bf16* __restrict__ g1,
                                                            const __bf16* __restrict__ W3t,
                                                            __bf16* __restrict__ g2) {
    constexpr int K = 128, NOUT = 64, L = K / 8;
    __shared__ __bf16 zs[16][K + 4];
    int tid = threadIdx.x;
    int rloc = tid / L;
    int f8 = (tid % L) * 8;
    int rglob = blockIdx.x * 16 + rloc;
    int d = deg[rglob];
    const int2* er = ell + (size_t)rglob * ELLCAP;
    float acc[8] = {};
#pragma unroll 8
    for (int e = 0; e < d; e++) {
        int2 cw = er[e];
        float w = __int_as_float(cw.y);
        bf16x8 hv = *(const bf16x8*)(g1 + (size_t)cw.x * K + f8);
#pragma unroll
        for (int j = 0; j < 8; j++) acc[j] = fmaf(w, (float)hv[j], acc[j]);
    }
    bf16x8 o;
#pragma unroll
    for (int j = 0; j < 8; j++) o[j] = (__bf16)tanhf(acc[j]);
    *(bf16x8*)&zs[rloc][f8] = o;
    __syncthreads();
    int wave = tid >> 6, lane = tid & 63;
    int lr = lane & 15, kg = lane >> 4;
    f32x4 c = (f32x4){0.f, 0.f, 0.f, 0.f};
#pragma unroll
    for (int ks = 0; ks < K / 32; ks++) {
        bf16x8 a = *(const bf16x8*)&zs[lr][ks * 32 + kg * 8];
        bf16x8 b = *(const bf16x8*)(W3t + (size_t)(wave * 16 + lr) * K + ks * 32 + kg * 8);
        c = __builtin_amdgcn_mfma_f32_16x16x32_bf16(a, b, c, 0, 0, 0);
    }
#pragma unroll
    for (int r = 0; r < 4; r++)
        g2[(size_t)(blockIdx.x * 16 + kg * 4 + r) * NOUT + wave * 16 + lr] = (__bf16)c[r];
}

// ---------------- SpMM F=64, bf16 out only (t = S . g2) ----------------
__global__ __launch_bounds__(256) void spmm64(const int* __restrict__ deg,
                                              const int2* __restrict__ ell,
                                              const __bf16* __restrict__ h,
                                              __bf16* __restrict__ z) {
    int r = blockIdx.x * 32 + threadIdx.x / 8;
    int f8 = (threadIdx.x & 7) * 8;
    int d = deg[r];
    const int2* er = ell + (size_t)r * ELLCAP;
    float acc[8] = {};
#pragma unroll 8
    for (int e = 0; e < d; e++) {
        int2 cw = er[e];
        float w = __int_as_float(cw.y);
        bf16x8 hv = *(const bf16x8*)(h + (size_t)cw.x * 64 + f8);
#pragma unroll
        for (int j = 0; j < 8; j++) acc[j] = fmaf(w, (float)hv[j], acc[j]);
    }
    bf16x8 o;
#pragma unroll
    for (int j = 0; j < 8; j++) o[j] = (__bf16)acc[j];
    *(bf16x8*)(z + (size_t)r * 64 + f8) = o;
}

// ---------------- final SpMM F=64: z = S . t -> z_igae f32 + Zb bf16 ----------------
__global__ __launch_bounds__(256) void spmm_final(const int* __restrict__ deg,
                                                  const int2* __restrict__ ell,
                                                  const __bf16* __restrict__ h,
                                                  __bf16* __restrict__ z,
                                                  float* __restrict__ zf) {
    int r = blockIdx.x * 32 + threadIdx.x / 8;
    int f8 = (threadIdx.x & 7) * 8;
    int d = deg[r];
    const int2* er = ell + (size_t)r * ELLCAP;
    float acc[8] = {};
#pragma unroll 8
    for (int e = 0; e < d; e++) {
        int2 cw = er[e];
        float w = __int_as_float(cw.y);
        bf16x8 hv = *(const bf16x8*)(h + (size_t)cw.x * 64 + f8);
#pragma unroll
        for (int j = 0; j < 8; j++) acc[j] = fmaf(w, (float)hv[j], acc[j]);
    }
    bf16x8 o;
#pragma unroll
    for (int j = 0; j < 8; j++) o[j] = (__bf16)acc[j];
    *(bf16x8*)(z + (size_t)r * 64 + f8) = o;
    f32x4 o0, o1;
#pragma unroll
    for (int j = 0; j < 4; j++) { o0[j] = acc[j]; o1[j] = acc[4 + j]; }
    *(f32x4*)(zf + (size_t)r * 64 + f8) = o0;
    *(f32x4*)(zf + (size_t)r * 64 + f8 + 4) = o1;
}

// ---------------- adj = sigmoid(Z Z^T): STREAMING 1-wave blocks + NT stores ----------
// Unified theory of all zzt datapoints: r14's streaming structure lost (202us)
// because REGULAR stores write-allocated adj into L2, evicting the 1.5MB Z
// working set -> its 680MB of re-reads went to HBM. r16 proved nt stores fix
// write-side RFO (144->123). Combining both: nt keeps adj out of L2 entirely ->
// Z stays L2-resident -> re-reads hit at 34 TB/s; 1-wave blocks (16.6KB LDS,
// 9 blocks/CU) give independently-phased store streams like the 6.7 TB/s
// poison-fill. Zero barriers; wave-local LDS transpose; fire-and-forget rows.
__global__ __launch_bounds__(64, 2) void zzt_sigmoid(const __bf16* __restrict__ Z,
                                                     float* __restrict__ out) {
    __shared__ float tile[16][260];  // 16.6 KB
    int lane = threadIdx.x;
    int lr = lane & 15;
    int kg = lane >> 4;
    int r0 = blockIdx.y * 16;   // wave's 16 rows
    int c0 = blockIdx.x * 256;  // wave's 256 cols
    bf16x8 af0 = *(const bf16x8*)(Z + (size_t)(r0 + lr) * 64 + kg * 8);
    bf16x8 af1 = *(const bf16x8*)(Z + (size_t)(r0 + lr) * 64 + 32 + kg * 8);
    f32x4 acc[16];
#pragma unroll
    for (int ni = 0; ni < 16; ni++) acc[ni] = (f32x4){0.f, 0.f, 0.f, 0.f};
#pragma unroll
    for (int ni = 0; ni < 16; ni++) {
        bf16x8 b0 = *(const bf16x8*)(Z + (size_t)(c0 + ni * 16 + lr) * 64 + kg * 8);
        bf16x8 b1 = *(const bf16x8*)(Z + (size_t)(c0 + ni * 16 + lr) * 64 + 32 + kg * 8);
        acc[ni] = __builtin_amdgcn_mfma_f32_16x16x32_bf16(af0, b0, acc[ni], 0, 0, 0);
        acc[ni] = __builtin_amdgcn_mfma_f32_16x16x32_bf16(af1, b1, acc[ni], 0, 0, 0);
    }
    // sigmoid -> LDS. C/D layout (m89-verified): col = lane&15, row = (lane>>4)*4 + reg
#pragma unroll
    for (int ni = 0; ni < 16; ni++) {
#pragma unroll
        for (int r = 0; r < 4; r++) {
            float e = __expf(-acc[ni][r]);
            tile[kg * 4 + r][ni * 16 + lr] = __builtin_amdgcn_rcpf(1.f + e);
        }
    }
    // implicit lgkmcnt wait (same-wave); 16 x 1KB nontemporal full-row stores.
#pragma unroll
    for (int rl = 0; rl < 16; rl++) {
        f32x4 v = *(const f32x4*)&tile[rl][lane * 4];
        __builtin_nontemporal_store(v, (f32x4*)(out + (size_t)(r0 + rl) * NNODES + c0 + lane * 4));
    }
}

extern "C" void kernel_launch(void* const* d_in, const int* in_sizes, int n_in,
                              void* d_out, int out_size, void* d_ws, size_t ws_size,
                              hipStream_t stream) {
    (void)in_sizes; (void)n_in; (void)out_size; (void)ws_size;
    const float* x  = (const float*)d_in[0];
    const int* erow = (const int*)d_in[1];
    const int* ecol = (const int*)d_in[2];
    const float* ew = (const float*)d_in[3];
    const float* W1 = (const float*)d_in[4];
    const float* W2 = (const float*)d_in[5];
    const float* W3 = (const float*)d_in[6];
    float* z_igae = (float*)d_out;
    float* adj = (float*)d_out + (size_t)NNODES * 64;

    char* ws = (char*)d_ws;
    size_t off = 0;
    auto alloc = [&](size_t bytes) {
        void* p = ws + off;
        off += (bytes + 255) & ~(size_t)255;
        return p;
    };
    __bf16* W1t = (__bf16*)alloc((size_t)512 * 256 * 2);
    __bf16* W2t = (__bf16*)alloc((size_t)256 * 128 * 2);
    __bf16* W3t = (__bf16*)alloc((size_t)128 * 64 * 2);
    __bf16* h1  = (__bf16*)alloc((size_t)NNODES * 256 * 2);
    __bf16* g1  = (__bf16*)alloc((size_t)NNODES * 128 * 2);
    __bf16* g2  = (__bf16*)alloc((size_t)NNODES * 64 * 2);
    __bf16* t   = (__bf16*)alloc((size_t)NNODES * 64 * 2);
    __bf16* Zb  = (__bf16*)alloc((size_t)NNODES * 64 * 2);
    int* deg    = (int*)alloc(NNODES * 4);
    int2* ell   = (int2*)alloc((size_t)NNODES * ELLCAP * 8);

    // prep (zero deg + weight casts)
    prep_kernel<<<(NNODES + 512 * 256 + 256 * 128 + 128 * 64 + 255) / 256, 256, 0, stream>>>(
        W1, W2, W3, W1t, W2t, W3t, deg);
    // h1 = tanh(x@W1) + ELL scatter, concurrently
    gemm1_scatter<<<384 + NEDGES / 256, 256, 0, stream>>>(x, W1t, h1, erow, ecol, ew, deg, ell);
    // g1 = h1 @ W2
    gemm_mfma<false, 256><<<dim3(NNODES / 128, 2), 256, 0, stream>>>(h1, W2t, g1, 128);
    // h2 = tanh(S g1); g2 = h2 @ W3  (gather F=128)
    fused_spmm_tanh_gemm<<<NNODES / 16, 256, 0, stream>>>(deg, ell, g1, W3t, g2);
    // t = S g2
    spmm64<<<NNODES / 32, 256, 0, stream>>>(deg, ell, g2, t);
    // z_igae = S t (f32 + bf16 copy)
    spmm_final<<<NNODES / 32, 256, 0, stream>>>(deg, ell, t, Zb, z_igae);
    // adjacency reconstruction: streaming 1-wave blocks + nontemporal stores
    zzt_sigmoid<<<dim3(NNODES / 256, NNODES / 16), 64, 0, stream>>>((const __bf16*)Zb, adj);
}

// Round 19
// 225.891 us; speedup vs baseline: 1.1427x; 1.1427x over previous
//
#include <hip/hip_runtime.h>
#include <hip/hip_bf16.h>

#define NNODES 12288
#define NEDGES (NNODES * 32)
#define ELLCAP 128  // max degree ~60 (Poisson(32) tail over 12288 rows); 128 unreachable

typedef __attribute__((ext_vector_type(4))) float f32x4;
typedef __attribute__((ext_vector_type(8))) __bf16 bf16x8;

// ---------------- fused prep: zero deg + 3 weight transpose-casts ----------------
__global__ __launch_bounds__(256) void prep_kernel(const float* __restrict__ W1,
                                                   const float* __restrict__ W2,
                                                   const float* __restrict__ W3,
                                                   __bf16* __restrict__ W1t,
                                                   __bf16* __restrict__ W2t,
                                                   __bf16* __restrict__ W3t,
                                                   int* __restrict__ deg) {
    int i = blockIdx.x * 256 + threadIdx.x;
    if (i < NNODES) { deg[i] = 0; return; }
    int j = i - NNODES;
    if (j < 512 * 256) { W1t[(size_t)(j % 256) * 512 + j / 256] = (__bf16)W1[j]; return; }
    j -= 512 * 256;
    if (j < 256 * 128) { W2t[(size_t)(j % 128) * 256 + j / 128] = (__bf16)W2[j]; return; }
    j -= 256 * 128;
    if (j < 128 * 64) { W3t[(size_t)(j % 64) * 128 + j / 64] = (__bf16)W3[j]; return; }
}

// ---------------- merged: gemm1 (blocks 0..383) + ELL scatter (blocks 384..1919) ----
__global__ __launch_bounds__(256) void gemm1_scatter(const float* __restrict__ x,
                                                     const __bf16* __restrict__ W1t,
                                                     __bf16* __restrict__ h1,
                                                     const int* __restrict__ erow,
                                                     const int* __restrict__ ecol,
                                                     const float* __restrict__ ew,
                                                     int* __restrict__ deg,
                                                     int2* __restrict__ ell) {
    if (blockIdx.x >= 384) {
        int e = (blockIdx.x - 384) * 256 + threadIdx.x;
        int r = erow[e];
        int p = atomicAdd(&deg[r], 1);
        int2 cw; cw.x = ecol[e]; cw.y = __float_as_int(ew[e]);
        ell[(size_t)r * ELLCAP + p] = cw;
        return;
    }
    // gemm1: h1 = tanh(x @ W1), K=512, Nc=256, f32 A cast in-register.
    constexpr int K = 512, Nc = 256;
    int wave = threadIdx.x >> 6, lane = threadIdx.x & 63;
    int lr = lane & 15, kg = lane >> 4;
    int m0 = (blockIdx.x % 96) * 128 + wave * 32;
    int n0 = (blockIdx.x / 96) * 64;
    f32x4 acc[2][4];
#pragma unroll
    for (int mi = 0; mi < 2; mi++)
#pragma unroll
        for (int ni = 0; ni < 4; ni++) acc[mi][ni] = (f32x4){0.f, 0.f, 0.f, 0.f};
#pragma unroll
    for (int k0 = 0; k0 < K; k0 += 32) {
        bf16x8 af[2], bf[4];
#pragma unroll
        for (int mi = 0; mi < 2; mi++) {
            const float* ap = x + (size_t)(m0 + mi * 16 + lr) * K + k0 + kg * 8;
            f32x4 a0 = *(const f32x4*)ap;
            f32x4 a1 = *(const f32x4*)(ap + 4);
#pragma unroll
            for (int j = 0; j < 4; j++) { af[mi][j] = (__bf16)a0[j]; af[mi][4 + j] = (__bf16)a1[j]; }
        }
#pragma unroll
        for (int ni = 0; ni < 4; ni++)
            bf[ni] = *(const bf16x8*)(W1t + (size_t)(n0 + ni * 16 + lr) * K + k0 + kg * 8);
#pragma unroll
        for (int mi = 0; mi < 2; mi++)
#pragma unroll
            for (int ni = 0; ni < 4; ni++)
                acc[mi][ni] = __builtin_amdgcn_mfma_f32_16x16x32_bf16(af[mi], bf[ni], acc[mi][ni], 0, 0, 0);
    }
    // C/D layout (m89-verified): col = lane&15, row = (lane>>4)*4 + reg
#pragma unroll
    for (int mi = 0; mi < 2; mi++)
#pragma unroll
        for (int ni = 0; ni < 4; ni++) {
            int col = n0 + ni * 16 + lr;
            int rowb = m0 + mi * 16 + kg * 4;
#pragma unroll
            for (int r = 0; r < 4; r++)
                h1[(size_t)(rowb + r) * Nc + col] = (__bf16)tanhf(acc[mi][ni][r]);
        }
}

// ---------------- generic dense GEMM (for g1 = h1 @ W2): bf16 MFMA ----------------
template <bool TANH, int K>
__global__ __launch_bounds__(256) void gemm_mfma(const __bf16* __restrict__ A,
                                                 const __bf16* __restrict__ Wt,
                                                 __bf16* __restrict__ C, int Nc) {
    int wave = threadIdx.x >> 6, lane = threadIdx.x & 63;
    int lr = lane & 15, kg = lane >> 4;
    int m0 = blockIdx.x * 128 + wave * 32;
    int n0 = blockIdx.y * 64;
    f32x4 acc[2][4];
#pragma unroll
    for (int mi = 0; mi < 2; mi++)
#pragma unroll
        for (int ni = 0; ni < 4; ni++) acc[mi][ni] = (f32x4){0.f, 0.f, 0.f, 0.f};
#pragma unroll
    for (int k0 = 0; k0 < K; k0 += 32) {
        bf16x8 af[2], bf[4];
#pragma unroll
        for (int mi = 0; mi < 2; mi++)
            af[mi] = *(const bf16x8*)(A + (size_t)(m0 + mi * 16 + lr) * K + k0 + kg * 8);
#pragma unroll
        for (int ni = 0; ni < 4; ni++)
            bf[ni] = *(const bf16x8*)(Wt + (size_t)(n0 + ni * 16 + lr) * K + k0 + kg * 8);
#pragma unroll
        for (int mi = 0; mi < 2; mi++)
#pragma unroll
            for (int ni = 0; ni < 4; ni++)
                acc[mi][ni] = __builtin_amdgcn_mfma_f32_16x16x32_bf16(af[mi], bf[ni], acc[mi][ni], 0, 0, 0);
    }
#pragma unroll
    for (int mi = 0; mi < 2; mi++)
#pragma unroll
        for (int ni = 0; ni < 4; ni++) {
            int col = n0 + ni * 16 + lr;
            int rowb = m0 + mi * 16 + kg * 4;
#pragma unroll
            for (int r = 0; r < 4; r++) {
                float v = acc[mi][ni][r];
                if (TANH) v = tanhf(v);
                C[(size_t)(rowb + r) * Nc + col] = (__bf16)v;
            }
        }
}

// ---------------- fusedB: h2 = tanh(spmm_F128(g1)); g2 = h2 @ W3 ----------------
__global__ __launch_bounds__(256) void fused_spmm_tanh_gemm(const int* __restrict__ deg,
                                                            const int2* __restrict__ ell,
                                                            const __bf16* __restrict__ g1,
                                                            const __bf16* __restrict__ W3t,
                                                            __bf16* __restrict__ g2) {
    constexpr int K = 128, NOUT = 64, L = K / 8;
    __shared__ __bf16 zs[16][K + 4];
    int tid = threadIdx.x;
    int rloc = tid / L;
    int f8 = (tid % L) * 8;
    int rglob = blockIdx.x * 16 + rloc;
    int d = deg[rglob];
    const int2* er = ell + (size_t)rglob * ELLCAP;
    float acc[8] = {};
#pragma unroll 8
    for (int e = 0; e < d; e++) {
        int2 cw = er[e];
        float w = __int_as_float(cw.y);
        bf16x8 hv = *(const bf16x8*)(g1 + (size_t)cw.x * K + f8);
#pragma unroll
        for (int j = 0; j < 8; j++) acc[j] = fmaf(w, (float)hv[j], acc[j]);
    }
    bf16x8 o;
#pragma unroll
    for (int j = 0; j < 8; j++) o[j] = (__bf16)tanhf(acc[j]);
    *(bf16x8*)&zs[rloc][f8] = o;
    __syncthreads();
    int wave = tid >> 6, lane = tid & 63;
    int lr = lane & 15, kg = lane >> 4;
    f32x4 c = (f32x4){0.f, 0.f, 0.f, 0.f};
#pragma unroll
    for (int ks = 0; ks < K / 32; ks++) {
        bf16x8 a = *(const bf16x8*)&zs[lr][ks * 32 + kg * 8];
        bf16x8 b = *(const bf16x8*)(W3t + (size_t)(wave * 16 + lr) * K + ks * 32 + kg * 8);
        c = __builtin_amdgcn_mfma_f32_16x16x32_bf16(a, b, c, 0, 0, 0);
    }
#pragma unroll
    for (int r = 0; r < 4; r++)
        g2[(size_t)(blockIdx.x * 16 + kg * 4 + r) * NOUT + wave * 16 + lr] = (__bf16)c[r];
}

// ---------------- SpMM F=64, bf16 out only (t = S . g2) ----------------
__global__ __launch_bounds__(256) void spmm64(const int* __restrict__ deg,
                                              const int2* __restrict__ ell,
                                              const __bf16* __restrict__ h,
                                              __bf16* __restrict__ z) {
    int r = blockIdx.x * 32 + threadIdx.x / 8;
    int f8 = (threadIdx.x & 7) * 8;
    int d = deg[r];
    const int2* er = ell + (size_t)r * ELLCAP;
    float acc[8] = {};
#pragma unroll 8
    for (int e = 0; e < d; e++) {
        int2 cw = er[e];
        float w = __int_as_float(cw.y);
        bf16x8 hv = *(const bf16x8*)(h + (size_t)cw.x * 64 + f8);
#pragma unroll
        for (int j = 0; j < 8; j++) acc[j] = fmaf(w, (float)hv[j], acc[j]);
    }
    bf16x8 o;
#pragma unroll
    for (int j = 0; j < 8; j++) o[j] = (__bf16)acc[j];
    *(bf16x8*)(z + (size_t)r * 64 + f8) = o;
}

// ---------------- final SpMM F=64: z = S . t -> z_igae f32 + Zb bf16 ----------------
__global__ __launch_bounds__(256) void spmm_final(const int* __restrict__ deg,
                                                  const int2* __restrict__ ell,
                                                  const __bf16* __restrict__ h,
                                                  __bf16* __restrict__ z,
                                                  float* __restrict__ zf) {
    int r = blockIdx.x * 32 + threadIdx.x / 8;
    int f8 = (threadIdx.x & 7) * 8;
    int d = deg[r];
    const int2* er = ell + (size_t)r * ELLCAP;
    float acc[8] = {};
#pragma unroll 8
    for (int e = 0; e < d; e++) {
        int2 cw = er[e];
        float w = __int_as_float(cw.y);
        bf16x8 hv = *(const bf16x8*)(h + (size_t)cw.x * 64 + f8);
#pragma unroll
        for (int j = 0; j < 8; j++) acc[j] = fmaf(w, (float)hv[j], acc[j]);
    }
    bf16x8 o;
#pragma unroll
    for (int j = 0; j < 8; j++) o[j] = (__bf16)acc[j];
    *(bf16x8*)(z + (size_t)r * 64 + f8) = o;
    f32x4 o0, o1;
#pragma unroll
    for (int j = 0; j < 4; j++) { o0[j] = acc[j]; o1[j] = acc[4 + j]; }
    *(f32x4*)(zf + (size_t)r * 64 + f8) = o0;
    *(f32x4*)(zf + (size_t)r * 64 + f8 + 4) = o1;
}

// ---------------- adj = sigmoid(Z Z^T): 128x256 tile + XCD reuse + NT stores ----------
// zzt matrix of variants: {16x256,64x256,128x256} x {regular,nt}. Measured:
// 64x256/reg=144.5, 64x256/nt=123, 128x256/reg=~150, 16x256/*=187-211 (read-
// volume dominated). This is the untested best cell: 128x256 (226MB re-reads,
// XCD-local via grid layout) + nt (no RFO, adj never pollutes L2). Epilogue =
// r15's dbuf 16-row phases; barrier drains proven harmless (r17 null).
__global__ __launch_bounds__(512) void zzt_sigmoid(const __bf16* __restrict__ Z,
                                                   float* __restrict__ out) {
    __shared__ float tile[2][16][260];  // 33.3 KB
    int wave = threadIdx.x >> 6;
    int lane = threadIdx.x & 63;
    int lr = lane & 15;
    int kg = lane >> 4;
    int wr = wave >> 2, wc = wave & 3;
    int r0 = blockIdx.x * 128;  // row-block (x fastest: B-panel sharers consecutive,
    int c0 = blockIdx.y * 256;  //  A-panel sharers 96 apart -> same XCD)
    int rw = r0 + wr * 64;
    int cw = c0 + wc * 64;
    bf16x8 af[4][2], bfr[4][2];
#pragma unroll
    for (int i = 0; i < 4; i++)
#pragma unroll
        for (int ks = 0; ks < 2; ks++) {
            af[i][ks]  = *(const bf16x8*)(Z + (size_t)(rw + i * 16 + lr) * 64 + ks * 32 + kg * 8);
            bfr[i][ks] = *(const bf16x8*)(Z + (size_t)(cw + i * 16 + lr) * 64 + ks * 32 + kg * 8);
        }
    f32x4 acc[4][4];
#pragma unroll
    for (int mi = 0; mi < 4; mi++)
#pragma unroll
        for (int ni = 0; ni < 4; ni++) acc[mi][ni] = (f32x4){0.f, 0.f, 0.f, 0.f};
#pragma unroll
    for (int mi = 0; mi < 4; mi++)
#pragma unroll
        for (int ni = 0; ni < 4; ni++) {
            acc[mi][ni] = __builtin_amdgcn_mfma_f32_16x16x32_bf16(af[mi][0], bfr[ni][0], acc[mi][ni], 0, 0, 0);
            acc[mi][ni] = __builtin_amdgcn_mfma_f32_16x16x32_bf16(af[mi][1], bfr[ni][1], acc[mi][ni], 0, 0, 0);
        }
    // phase p covers block rows [p*16, p*16+16): filled by waves with wr==p>>2,
    // fragment mi=p&3. C/D: col = lane&15, row = (lane>>4)*4+reg.
    if (wr == 0) {
#pragma unroll
        for (int ni = 0; ni < 4; ni++)
#pragma unroll
            for (int r = 0; r < 4; r++) {
                float e = __expf(-acc[0][ni][r]);
                tile[0][kg * 4 + r][wc * 64 + ni * 16 + lr] = __builtin_amdgcn_rcpf(1.f + e);
            }
    }
    __syncthreads();
#pragma unroll
    for (int p = 0; p < 8; p++) {
        if (p < 7 && wr == ((p + 1) >> 2)) {
#pragma unroll
            for (int ni = 0; ni < 4; ni++)
#pragma unroll
                for (int r = 0; r < 4; r++) {
                    float e = __expf(-acc[(p + 1) & 3][ni][r]);
                    tile[(p + 1) & 1][kg * 4 + r][wc * 64 + ni * 16 + lr] = __builtin_amdgcn_rcpf(1.f + e);
                }
        }
        // stores: 16 rows / 8 waves = 2 rows each, full 1KB nontemporal rows
#pragma unroll
        for (int it = 0; it < 2; it++) {
            int rowl = it * 8 + wave;
            size_t grow = (size_t)(r0 + p * 16 + rowl);
            f32x4 v = *(const f32x4*)&tile[p & 1][rowl][lane * 4];
            __builtin_nontemporal_store(v, (f32x4*)(out + grow * NNODES + c0 + lane * 4));
        }
        __syncthreads();
    }
}

extern "C" void kernel_launch(void* const* d_in, const int* in_sizes, int n_in,
                              void* d_out, int out_size, void* d_ws, size_t ws_size,
                              hipStream_t stream) {
    (void)in_sizes; (void)n_in; (void)out_size; (void)ws_size;
    const float* x  = (const float*)d_in[0];
    const int* erow = (const int*)d_in[1];
    const int* ecol = (const int*)d_in[2];
    const float* ew = (const float*)d_in[3];
    const float* W1 = (const float*)d_in[4];
    const float* W2 = (const float*)d_in[5];
    const float* W3 = (const float*)d_in[6];
    float* z_igae = (float*)d_out;
    float* adj = (float*)d_out + (size_t)NNODES * 64;

    char* ws = (char*)d_ws;
    size_t off = 0;
    auto alloc = [&](size_t bytes) {
        void* p = ws + off;
        off += (bytes + 255) & ~(size_t)255;
        return p;
    };
    __bf16* W1t = (__bf16*)alloc((size_t)512 * 256 * 2);
    __bf16* W2t = (__bf16*)alloc((size_t)256 * 128 * 2);
    __bf16* W3t = (__bf16*)alloc((size_t)128 * 64 * 2);
    __bf16* h1  = (__bf16*)alloc((size_t)NNODES * 256 * 2);
    __bf16* g1  = (__bf16*)alloc((size_t)NNODES * 128 * 2);
    __bf16* g2  = (__bf16*)alloc((size_t)NNODES * 64 * 2);
    __bf16* t   = (__bf16*)alloc((size_t)NNODES * 64 * 2);
    __bf16* Zb  = (__bf16*)alloc((size_t)NNODES * 64 * 2);
    int* deg    = (int*)alloc(NNODES * 4);
    int2* ell   = (int2*)alloc((size_t)NNODES * ELLCAP * 8);

    // prep (zero deg + weight casts)
    prep_kernel<<<(NNODES + 512 * 256 + 256 * 128 + 128 * 64 + 255) / 256, 256, 0, stream>>>(
        W1, W2, W3, W1t, W2t, W3t, deg);
    // h1 = tanh(x@W1) + ELL scatter, concurrently
    gemm1_scatter<<<384 + NEDGES / 256, 256, 0, stream>>>(x, W1t, h1, erow, ecol, ew, deg, ell);
    // g1 = h1 @ W2
    gemm_mfma<false, 256><<<dim3(NNODES / 128, 2), 256, 0, stream>>>(h1, W2t, g1, 128);
    // h2 = tanh(S g1); g2 = h2 @ W3  (gather F=128)
    fused_spmm_tanh_gemm<<<NNODES / 16, 256, 0, stream>>>(deg, ell, g1, W3t, g2);
    // t = S g2
    spmm64<<<NNODES / 32, 256, 0, stream>>>(deg, ell, g2, t);
    // z_igae = S t (f32 + bf16 copy)
    spmm_final<<<NNODES / 32, 256, 0, stream>>>(deg, ell, t, Zb, z_igae);
    // adjacency reconstruction: 128x256 XCD-aware tiles + nontemporal row stores
    zzt_sigmoid<<<dim3(NNODES / 128, NNODES / 256), 512, 0, stream>>>((const __bf16*)Zb, adj);
}

// Round 20
// 193.995 us; speedup vs baseline: 1.3306x; 1.1644x over previous
//
#include <hip/hip_runtime.h>
#include <hip/hip_bf16.h>

#define NNODES 12288
#define NEDGES (NNODES * 32)
#define ELLCAP 128  // max degree ~60 (Poisson(32) tail over 12288 rows); 128 unreachable

typedef __attribute__((ext_vector_type(4))) float f32x4;
typedef __attribute__((ext_vector_type(8))) __bf16 bf16x8;

// ---------------- fused prep: zero deg + 3 weight transpose-casts ----------------
__global__ __launch_bounds__(256) void prep_kernel(const float* __restrict__ W1,
                                                   const float* __restrict__ W2,
                                                   const float* __restrict__ W3,
                                                   __bf16* __restrict__ W1t,
                                                   __bf16* __restrict__ W2t,
                                                   __bf16* __restrict__ W3t,
                                                   int* __restrict__ deg) {
    int i = blockIdx.x * 256 + threadIdx.x;
    if (i < NNODES) { deg[i] = 0; return; }
    int j = i - NNODES;
    if (j < 512 * 256) { W1t[(size_t)(j % 256) * 512 + j / 256] = (__bf16)W1[j]; return; }
    j -= 512 * 256;
    if (j < 256 * 128) { W2t[(size_t)(j % 128) * 256 + j / 128] = (__bf16)W2[j]; return; }
    j -= 256 * 128;
    if (j < 128 * 64) { W3t[(size_t)(j % 64) * 128 + j / 64] = (__bf16)W3[j]; return; }
}

// ---------------- merged: gemm1 (blocks 0..383) + ELL scatter (blocks 384..1919) ----
__global__ __launch_bounds__(256) void gemm1_scatter(const float* __restrict__ x,
                                                     const __bf16* __restrict__ W1t,
                                                     __bf16* __restrict__ h1,
                                                     const int* __restrict__ erow,
                                                     const int* __restrict__ ecol,
                                                     const float* __restrict__ ew,
                                                     int* __restrict__ deg,
                                                     int2* __restrict__ ell) {
    if (blockIdx.x >= 384) {
        int e = (blockIdx.x - 384) * 256 + threadIdx.x;
        int r = erow[e];
        int p = atomicAdd(&deg[r], 1);
        int2 cw; cw.x = ecol[e]; cw.y = __float_as_int(ew[e]);
        ell[(size_t)r * ELLCAP + p] = cw;
        return;
    }
    // gemm1: h1 = tanh(x @ W1), K=512, Nc=256, f32 A cast in-register.
    constexpr int K = 512, Nc = 256;
    int wave = threadIdx.x >> 6, lane = threadIdx.x & 63;
    int lr = lane & 15, kg = lane >> 4;
    int m0 = (blockIdx.x % 96) * 128 + wave * 32;
    int n0 = (blockIdx.x / 96) * 64;
    f32x4 acc[2][4];
#pragma unroll
    for (int mi = 0; mi < 2; mi++)
#pragma unroll
        for (int ni = 0; ni < 4; ni++) acc[mi][ni] = (f32x4){0.f, 0.f, 0.f, 0.f};
#pragma unroll
    for (int k0 = 0; k0 < K; k0 += 32) {
        bf16x8 af[2], bf[4];
#pragma unroll
        for (int mi = 0; mi < 2; mi++) {
            const float* ap = x + (size_t)(m0 + mi * 16 + lr) * K + k0 + kg * 8;
            f32x4 a0 = *(const f32x4*)ap;
            f32x4 a1 = *(const f32x4*)(ap + 4);
#pragma unroll
            for (int j = 0; j < 4; j++) { af[mi][j] = (__bf16)a0[j]; af[mi][4 + j] = (__bf16)a1[j]; }
        }
#pragma unroll
        for (int ni = 0; ni < 4; ni++)
            bf[ni] = *(const bf16x8*)(W1t + (size_t)(n0 + ni * 16 + lr) * K + k0 + kg * 8);
#pragma unroll
        for (int mi = 0; mi < 2; mi++)
#pragma unroll
            for (int ni = 0; ni < 4; ni++)
                acc[mi][ni] = __builtin_amdgcn_mfma_f32_16x16x32_bf16(af[mi], bf[ni], acc[mi][ni], 0, 0, 0);
    }
    // C/D layout (m89-verified): col = lane&15, row = (lane>>4)*4 + reg
#pragma unroll
    for (int mi = 0; mi < 2; mi++)
#pragma unroll
        for (int ni = 0; ni < 4; ni++) {
            int col = n0 + ni * 16 + lr;
            int rowb = m0 + mi * 16 + kg * 4;
#pragma unroll
            for (int r = 0; r < 4; r++)
                h1[(size_t)(rowb + r) * Nc + col] = (__bf16)tanhf(acc[mi][ni][r]);
        }
}

// ---------------- generic dense GEMM (for g1 = h1 @ W2): bf16 MFMA ----------------
template <bool TANH, int K>
__global__ __launch_bounds__(256) void gemm_mfma(const __bf16* __restrict__ A,
                                                 const __bf16* __restrict__ Wt,
                                                 __bf16* __restrict__ C, int Nc) {
    int wave = threadIdx.x >> 6, lane = threadIdx.x & 63;
    int lr = lane & 15, kg = lane >> 4;
    int m0 = blockIdx.x * 128 + wave * 32;
    int n0 = blockIdx.y * 64;
    f32x4 acc[2][4];
#pragma unroll
    for (int mi = 0; mi < 2; mi++)
#pragma unroll
        for (int ni = 0; ni < 4; ni++) acc[mi][ni] = (f32x4){0.f, 0.f, 0.f, 0.f};
#pragma unroll
    for (int k0 = 0; k0 < K; k0 += 32) {
        bf16x8 af[2], bf[4];
#pragma unroll
        for (int mi = 0; mi < 2; mi++)
            af[mi] = *(const bf16x8*)(A + (size_t)(m0 + mi * 16 + lr) * K + k0 + kg * 8);
#pragma unroll
        for (int ni = 0; ni < 4; ni++)
            bf[ni] = *(const bf16x8*)(Wt + (size_t)(n0 + ni * 16 + lr) * K + k0 + kg * 8);
#pragma unroll
        for (int mi = 0; mi < 2; mi++)
#pragma unroll
            for (int ni = 0; ni < 4; ni++)
                acc[mi][ni] = __builtin_amdgcn_mfma_f32_16x16x32_bf16(af[mi], bf[ni], acc[mi][ni], 0, 0, 0);
    }
#pragma unroll
    for (int mi = 0; mi < 2; mi++)
#pragma unroll
        for (int ni = 0; ni < 4; ni++) {
            int col = n0 + ni * 16 + lr;
            int rowb = m0 + mi * 16 + kg * 4;
#pragma unroll
            for (int r = 0; r < 4; r++) {
                float v = acc[mi][ni][r];
                if (TANH) v = tanhf(v);
                C[(size_t)(rowb + r) * Nc + col] = (__bf16)v;
            }
        }
}

// ---------------- fusedB: h2 = tanh(spmm_F128(g1)); g2 = h2 @ W3 ----------------
__global__ __launch_bounds__(256) void fused_spmm_tanh_gemm(const int* __restrict__ deg,
                                                            const int2* __restrict__ ell,
                                                            const __bf16* __restrict__ g1,
                                                            const __bf16* __restrict__ W3t,
                                                            __bf16* __restrict__ g2) {
    constexpr int K = 128, NOUT = 64, L = K / 8;
    __shared__ __bf16 zs[16][K + 4];
    int tid = threadIdx.x;
    int rloc = tid / L;
    int f8 = (tid % L) * 8;
    int rglob = blockIdx.x * 16 + rloc;
    int d = deg[rglob];
    const int2* er = ell + (size_t)rglob * ELLCAP;
    float acc[8] = {};
#pragma unroll 8
    for (int e = 0; e < d; e++) {
        int2 cw = er[e];
        float w = __int_as_float(cw.y);
        bf16x8 hv = *(const bf16x8*)(g1 + (size_t)cw.x * K + f8);
#pragma unroll
        for (int j = 0; j < 8; j++) acc[j] = fmaf(w, (float)hv[j], acc[j]);
    }
    bf16x8 o;
#pragma unroll
    for (int j = 0; j < 8; j++) o[j] = (__bf16)tanhf(acc[j]);
    *(bf16x8*)&zs[rloc][f8] = o;
    __syncthreads();
    int wave = tid >> 6, lane = tid & 63;
    int lr = lane & 15, kg = lane >> 4;
    f32x4 c = (f32x4){0.f, 0.f, 0.f, 0.f};
#pragma unroll
    for (int ks = 0; ks < K / 32; ks++) {
        bf16x8 a = *(const bf16x8*)&zs[lr][ks * 32 + kg * 8];
        bf16x8 b = *(const bf16x8*)(W3t + (size_t)(wave * 16 + lr) * K + ks * 32 + kg * 8);
        c = __builtin_amdgcn_mfma_f32_16x16x32_bf16(a, b, c, 0, 0, 0);
    }
#pragma unroll
    for (int r = 0; r < 4; r++)
        g2[(size_t)(blockIdx.x * 16 + kg * 4 + r) * NOUT + wave * 16 + lr] = (__bf16)c[r];
}

// ---------------- SpMM F=64, bf16 out only (t = S . g2) ----------------
__global__ __launch_bounds__(256) void spmm64(const int* __restrict__ deg,
                                              const int2* __restrict__ ell,
                                              const __bf16* __restrict__ h,
                                              __bf16* __restrict__ z) {
    int r = blockIdx.x * 32 + threadIdx.x / 8;
    int f8 = (threadIdx.x & 7) * 8;
    int d = deg[r];
    const int2* er = ell + (size_t)r * ELLCAP;
    float acc[8] = {};
#pragma unroll 8
    for (int e = 0; e < d; e++) {
        int2 cw = er[e];
        float w = __int_as_float(cw.y);
        bf16x8 hv = *(const bf16x8*)(h + (size_t)cw.x * 64 + f8);
#pragma unroll
        for (int j = 0; j < 8; j++) acc[j] = fmaf(w, (float)hv[j], acc[j]);
    }
    bf16x8 o;
#pragma unroll
    for (int j = 0; j < 8; j++) o[j] = (__bf16)acc[j];
    *(bf16x8*)(z + (size_t)r * 64 + f8) = o;
}

// ---------------- final SpMM F=64: z = S . t -> z_igae f32 + Zb bf16 ----------------
__global__ __launch_bounds__(256) void spmm_final(const int* __restrict__ deg,
                                                  const int2* __restrict__ ell,
                                                  const __bf16* __restrict__ h,
                                                  __bf16* __restrict__ z,
                                                  float* __restrict__ zf) {
    int r = blockIdx.x * 32 + threadIdx.x / 8;
    int f8 = (threadIdx.x & 7) * 8;
    int d = deg[r];
    const int2* er = ell + (size_t)r * ELLCAP;
    float acc[8] = {};
#pragma unroll 8
    for (int e = 0; e < d; e++) {
        int2 cw = er[e];
        float w = __int_as_float(cw.y);
        bf16x8 hv = *(const bf16x8*)(h + (size_t)cw.x * 64 + f8);
#pragma unroll
        for (int j = 0; j < 8; j++) acc[j] = fmaf(w, (float)hv[j], acc[j]);
    }
    bf16x8 o;
#pragma unroll
    for (int j = 0; j < 8; j++) o[j] = (__bf16)acc[j];
    *(bf16x8*)(z + (size_t)r * 64 + f8) = o;
    f32x4 o0, o1;
#pragma unroll
    for (int j = 0; j < 4; j++) { o0[j] = acc[j]; o1[j] = acc[4 + j]; }
    *(f32x4*)(zf + (size_t)r * 64 + f8) = o0;
    *(f32x4*)(zf + (size_t)r * 64 + f8 + 4) = o1;
}

// ---------------- adj = sigmoid(Z Z^T): r8 structure + NONTEMPORAL row stores ----
// FINAL (r19 closed the design matrix): 64x256 4-wave tile + dbuf 16-row phases
// + nt full-1KB-row stores = best measured cell (zzt ~123us; total 194us).
// nt kills write-RFO (+21us) and keeps adj out of L2 so the 1.5MB Z working set
// stays resident; 256-thr blocks give 4 independently-phased store streams/CU
// (512-thr/2-block variants regress; barrier-drain removal was null).
__global__ __launch_bounds__(256) void zzt_sigmoid(const __bf16* __restrict__ Z,
                                                   float* __restrict__ out) {
    __shared__ float tile[2][16][260];  // 33.3 KB
    int wave = threadIdx.x >> 6;
    int lane = threadIdx.x & 63;
    int lr = lane & 15;
    int kg = lane >> 4;
    int r0 = blockIdx.y * 64;
    int c0blk = blockIdx.x * 256;
    int c0 = c0blk + wave * 64;
    bf16x8 af[4][2], bfr[4][2];
#pragma unroll
    for (int i = 0; i < 4; i++)
#pragma unroll
        for (int ks = 0; ks < 2; ks++) {
            af[i][ks]  = *(const bf16x8*)(Z + (size_t)(r0 + i * 16 + lr) * 64 + ks * 32 + kg * 8);
            bfr[i][ks] = *(const bf16x8*)(Z + (size_t)(c0 + i * 16 + lr) * 64 + ks * 32 + kg * 8);
        }
    f32x4 acc[4][4];
#pragma unroll
    for (int mi = 0; mi < 4; mi++)
#pragma unroll
        for (int ni = 0; ni < 4; ni++) acc[mi][ni] = (f32x4){0.f, 0.f, 0.f, 0.f};
#pragma unroll
    for (int mi = 0; mi < 4; mi++)
#pragma unroll
        for (int ni = 0; ni < 4; ni++) {
            acc[mi][ni] = __builtin_amdgcn_mfma_f32_16x16x32_bf16(af[mi][0], bfr[ni][0], acc[mi][ni], 0, 0, 0);
            acc[mi][ni] = __builtin_amdgcn_mfma_f32_16x16x32_bf16(af[mi][1], bfr[ni][1], acc[mi][ni], 0, 0, 0);
        }
#pragma unroll
    for (int ni = 0; ni < 4; ni++) {
        int colb = wave * 64 + ni * 16 + lr;
#pragma unroll
        for (int r = 0; r < 4; r++) {
            float e = __expf(-acc[0][ni][r]);
            tile[0][kg * 4 + r][colb] = __builtin_amdgcn_rcpf(1.f + e);
        }
    }
    __syncthreads();
#pragma unroll
    for (int p = 0; p < 4; p++) {
        if (p < 3) {
#pragma unroll
            for (int ni = 0; ni < 4; ni++) {
                int colb = wave * 64 + ni * 16 + lr;
#pragma unroll
                for (int r = 0; r < 4; r++) {
                    float e = __expf(-acc[p + 1][ni][r]);
                    tile[(p + 1) & 1][kg * 4 + r][colb] = __builtin_amdgcn_rcpf(1.f + e);
                }
            }
        }
#pragma unroll
        for (int it = 0; it < 4; it++) {
            int rowl = it * 4 + wave;
            size_t grow = (size_t)(r0 + p * 16 + rowl);
            f32x4 v = *(const f32x4*)&tile[p & 1][rowl][lane * 4];
            __builtin_nontemporal_store(v, (f32x4*)(out + grow * NNODES + c0blk + lane * 4));
        }
        __syncthreads();
    }
}

extern "C" void kernel_launch(void* const* d_in, const int* in_sizes, int n_in,
                              void* d_out, int out_size, void* d_ws, size_t ws_size,
                              hipStream_t stream) {
    (void)in_sizes; (void)n_in; (void)out_size; (void)ws_size;
    const float* x  = (const float*)d_in[0];
    const int* erow = (const int*)d_in[1];
    const int* ecol = (const int*)d_in[2];
    const float* ew = (const float*)d_in[3];
    const float* W1 = (const float*)d_in[4];
    const float* W2 = (const float*)d_in[5];
    const float* W3 = (const float*)d_in[6];
    float* z_igae = (float*)d_out;
    float* adj = (float*)d_out + (size_t)NNODES * 64;

    char* ws = (char*)d_ws;
    size_t off = 0;
    auto alloc = [&](size_t bytes) {
        void* p = ws + off;
        off += (bytes + 255) & ~(size_t)255;
        return p;
    };
    __bf16* W1t = (__bf16*)alloc((size_t)512 * 256 * 2);
    __bf16* W2t = (__bf16*)alloc((size_t)256 * 128 * 2);
    __bf16* W3t = (__bf16*)alloc((size_t)128 * 64 * 2);
    __bf16* h1  = (__bf16*)alloc((size_t)NNODES * 256 * 2);
    __bf16* g1  = (__bf16*)alloc((size_t)NNODES * 128 * 2);
    __bf16* g2  = (__bf16*)alloc((size_t)NNODES * 64 * 2);
    __bf16* t   = (__bf16*)alloc((size_t)NNODES * 64 * 2);
    __bf16* Zb  = (__bf16*)alloc((size_t)NNODES * 64 * 2);
    int* deg    = (int*)alloc(NNODES * 4);
    int2* ell   = (int2*)alloc((size_t)NNODES * ELLCAP * 8);

    // prep (zero deg + weight casts)
    prep_kernel<<<(NNODES + 512 * 256 + 256 * 128 + 128 * 64 + 255) / 256, 256, 0, stream>>>(
        W1, W2, W3, W1t, W2t, W3t, deg);
    // h1 = tanh(x@W1) + ELL scatter, concurrently
    gemm1_scatter<<<384 + NEDGES / 256, 256, 0, stream>>>(x, W1t, h1, erow, ecol, ew, deg, ell);
    // g1 = h1 @ W2
    gemm_mfma<false, 256><<<dim3(NNODES / 128, 2), 256, 0, stream>>>(h1, W2t, g1, 128);
    // h2 = tanh(S g1); g2 = h2 @ W3  (gather F=128)
    fused_spmm_tanh_gemm<<<NNODES / 16, 256, 0, stream>>>(deg, ell, g1, W3t, g2);
    // t = S g2
    spmm64<<<NNODES / 32, 256, 0, stream>>>(deg, ell, g2, t);
    // z_igae = S t (f32 + bf16 copy)
    spmm_final<<<NNODES / 32, 256, 0, stream>>>(deg, ell, t, Zb, z_igae);
    // adjacency reconstruction: r8 structure + nontemporal full-row stores
    zzt_sigmoid<<<dim3(NNODES / 256, NNODES / 64), 256, 0, stream>>>((const __bf16*)Zb, adj);
}